// Round 3
// baseline (183.202 us; speedup 1.0000x reference)
//
#include <hip/hip_runtime.h>
#include <math.h>

typedef unsigned int uint;
typedef unsigned short ushort;

using short8 = __attribute__((ext_vector_type(8))) short;
using f32x4  = __attribute__((ext_vector_type(4))) float;

#define BT      65536
#define HID     512
#define IN_DIM  594
#define TRUNK   256
#define BINS    20
#define NKCH    19
#define NCOMBO  320

#define WT_P_SZ (19*16*64*8)
#define RP_SZ   (16*64*8)
#define WA_P_SZ (8*20*64*8)

__device__ inline ushort f2bf(float f) {
    uint u = __float_as_uint(f);
    return (ushort)((u + 0x7fffu + ((u >> 16) & 1u)) >> 16);   // RNE
}

// ---------------------------------------------------------------------------
// Pack weights to bf16 MFMA B-fragment layout (verified in R2):
//   frag elem j, lane l, frag (kk,n): B[k][col], k=kk*32+(l>>4)*8+j, col=n*16+(l&15)
// ---------------------------------------------------------------------------
__global__ __launch_bounds__(64) void pack_all(
    const float* __restrict__ trunk_w, const float* __restrict__ router_w,
    const float* __restrict__ inst_base_w, const float* __restrict__ inst_base_b,
    const float* __restrict__ group_base_w, const float* __restrict__ group_base_b,
    const float* __restrict__ inst_exp_w, const float* __restrict__ inst_exp_b,
    const float* __restrict__ group_exp_w, const float* __restrict__ group_exp_b,
    ushort* __restrict__ WtP, ushort* __restrict__ RP,
    ushort* __restrict__ WaP, float* __restrict__ wbias)
{
    const int b = blockIdx.x, l = threadIdx.x;
    const int lr = l & 15, lg = l >> 4;
    if (b < 304) {                      // trunk: kk 0..18, n 0..15
        int kk = b >> 4, n = b & 15;
        int col = n * 16 + lr;
        ushort* dst = WtP + ((size_t)(kk * 16 + n) * 64 + l) * 8;
        #pragma unroll
        for (int j = 0; j < 8; ++j) {
            int k = kk * 32 + lg * 8 + j;
            dst[j] = (k < IN_DIM) ? f2bf(trunk_w[k * TRUNK + col]) : (ushort)0;
        }
    } else if (b < 320) {               // router: kk 0..15
        int kk = b - 304;
        ushort* dst = RP + ((size_t)(kk * 64 + l)) * 8;
        #pragma unroll
        for (int j = 0; j < 8; ++j) {
            int k = kk * 32 + lg * 8 + j;
            dst[j] = (lr < 7) ? f2bf(router_w[k * 7 + lr]) : (ushort)0;
        }
    } else if (b < 480) {               // heads: kk 0..7, n 0..19
        int b2 = b - 320, kk = b2 / 20, n = b2 % 20;
        int combo = n * 16 + lr;
        int h = combo / 160, rem = combo % 160, kb = rem >> 3, p = rem & 7;
        const float* bw = h ? group_base_w : inst_base_w;
        const float* ew = h ? group_exp_w  : inst_exp_w;
        ushort* dst = WaP + ((size_t)(kk * 20 + n) * 64 + l) * 8;
        #pragma unroll
        for (int j = 0; j < 8; ++j) {
            int k = kk * 32 + lg * 8 + j;
            float v = (p == 0) ? bw[k * BINS + kb]
                               : ew[((p - 1) * TRUNK + k) * BINS + kb];
            dst[j] = f2bf(v);
        }
    } else {                            // bias[320]
        for (int c = l; c < NCOMBO; c += 64) {
            int h = c / 160, rem = c % 160, kb = rem >> 3, p = rem & 7;
            const float* bb = h ? group_base_b : inst_base_b;
            const float* eb = h ? group_exp_b  : inst_exp_b;
            wbias[c] = (p == 0) ? bb[kb] : eb[(p - 1) * BINS + kb];
        }
    }
}

// ---------------------------------------------------------------------------
// Fused main: 128 tokens/block, 4 waves, wave w owns rows w*32..+31.
// A-fragments loaded DIRECTLY from global (no LDS staging, no barriers).
// LDS: zs[128][256] bf16, XOR-swizzled, wave-private rows.
// ---------------------------------------------------------------------------
__global__ __launch_bounds__(256, 2) void fused_mfma(
    const float* __restrict__ h_t, const float* __restrict__ a_t,
    const float* __restrict__ d_t, const float* __restrict__ age,
    const float* __restrict__ trunk_b, const float* __restrict__ router_b,
    const ushort* __restrict__ WtP, const ushort* __restrict__ RP,
    const ushort* __restrict__ WaP, const float* __restrict__ wbias,
    float* __restrict__ out)
{
    __shared__ alignas(16) ushort zs[128 * 256];   // 64 KB

    const int tid = threadIdx.x;
    const int l = tid & 63, w = tid >> 6;
    const int lr = l & 15, lg = l >> 4;
    const int block0 = blockIdx.x * 128;
    const size_t tok0 = block0 + w * 32 + lr;      // a0 row
    const size_t tok1 = tok0 + 16;                 // a1 row

    f32x4 acc[2][16];
    f32x4 accr[2];
    #pragma unroll
    for (int m = 0; m < 2; ++m) {
        accr[m] = (f32x4){0.f, 0.f, 0.f, 0.f};
        #pragma unroll
        for (int n = 0; n < 16; ++n) acc[m][n] = (f32x4){0.f, 0.f, 0.f, 0.f};
    }

    auto cvt8 = [](float4 a, float4 b) -> short8 {
        short8 v;
        v[0] = (short)f2bf(a.x); v[1] = (short)f2bf(a.y);
        v[2] = (short)f2bf(a.z); v[3] = (short)f2bf(a.w);
        v[4] = (short)f2bf(b.x); v[5] = (short)f2bf(b.y);
        v[6] = (short)f2bf(b.z); v[7] = (short)f2bf(b.w);
        return v;
    };

    // ---- phase A: trunk (K=608) + router (K=512), direct-global A ---------
    #pragma unroll 2
    for (int kk = 0; kk < 16; ++kk) {               // h_t chunks
        const float4* p0 = (const float4*)(h_t + tok0 * HID + kk * 32 + lg * 8);
        const float4* p1 = (const float4*)(h_t + tok1 * HID + kk * 32 + lg * 8);
        float4 f00 = p0[0], f01 = p0[1];
        float4 f10 = p1[0], f11 = p1[1];
        short8 a0 = cvt8(f00, f01);
        short8 a1 = cvt8(f10, f11);

        short8 rb = *(const short8*)(RP + ((size_t)(kk * 64 + l)) * 8);
        accr[0] = __builtin_amdgcn_mfma_f32_16x16x32_bf16(a0, rb, accr[0], 0, 0, 0);
        accr[1] = __builtin_amdgcn_mfma_f32_16x16x32_bf16(a1, rb, accr[1], 0, 0, 0);

        const ushort* wp = WtP + (size_t)kk * 16 * 64 * 8;
        #pragma unroll
        for (int n = 0; n < 16; ++n) {
            short8 bq = *(const short8*)(wp + ((size_t)n * 64 + l) * 8);
            acc[0][n] = __builtin_amdgcn_mfma_f32_16x16x32_bf16(a0, bq, acc[0][n], 0, 0, 0);
            acc[1][n] = __builtin_amdgcn_mfma_f32_16x16x32_bf16(a1, bq, acc[1][n], 0, 0, 0);
        }
    }
    #pragma unroll
    for (int kk = 16; kk < 18; ++kk) {              // a_t chunks
        const float4* p0 = (const float4*)(a_t + tok0 * 64 + (kk - 16) * 32 + lg * 8);
        const float4* p1 = (const float4*)(a_t + tok1 * 64 + (kk - 16) * 32 + lg * 8);
        float4 f00 = p0[0], f01 = p0[1];
        float4 f10 = p1[0], f11 = p1[1];
        short8 a0 = cvt8(f00, f01);
        short8 a1 = cvt8(f10, f11);
        const ushort* wp = WtP + (size_t)kk * 16 * 64 * 8;
        #pragma unroll
        for (int n = 0; n < 16; ++n) {
            short8 bq = *(const short8*)(wp + ((size_t)n * 64 + l) * 8);
            acc[0][n] = __builtin_amdgcn_mfma_f32_16x16x32_bf16(a0, bq, acc[0][n], 0, 0, 0);
            acc[1][n] = __builtin_amdgcn_mfma_f32_16x16x32_bf16(a1, bq, acc[1][n], 0, 0, 0);
        }
    }
    {                                               // tail chunk kk=18: d_t/age/pad
        short8 a0, a1;
        #pragma unroll
        for (int j = 0; j < 8; ++j) {
            int c = 576 + lg * 8 + j;
            float v0, v1;
            if (c < 578)      { v0 = d_t[tok0 * 2 + (c - 576)];  v1 = d_t[tok1 * 2 + (c - 576)]; }
            else if (c < 594) { v0 = age[tok0 * 16 + (c - 578)]; v1 = age[tok1 * 16 + (c - 578)]; }
            else              { v0 = 0.f; v1 = 0.f; }
            a0[j] = (short)f2bf(v0);
            a1[j] = (short)f2bf(v1);
        }
        const ushort* wp = WtP + (size_t)18 * 16 * 64 * 8;
        #pragma unroll
        for (int n = 0; n < 16; ++n) {
            short8 bq = *(const short8*)(wp + ((size_t)n * 64 + l) * 8);
            acc[0][n] = __builtin_amdgcn_mfma_f32_16x16x32_bf16(a0, bq, acc[0][n], 0, 0, 0);
            acc[1][n] = __builtin_amdgcn_mfma_f32_16x16x32_bf16(a1, bq, acc[1][n], 0, 0, 0);
        }
    }

    // ---- router softmax in registers --------------------------------------
    float pwv[2][4];
    {
        const float rb_l = (lr < 7) ? router_b[lr] : 0.f;
        #pragma unroll
        for (int m = 0; m < 2; ++m)
        #pragma unroll
        for (int r = 0; r < 4; ++r) {
            float x = (lr < 7) ? (accr[m][r] + rb_l) : -3.0e38f;
            float mx = x;
            mx = fmaxf(mx, __shfl_xor(mx, 1));
            mx = fmaxf(mx, __shfl_xor(mx, 2));
            mx = fmaxf(mx, __shfl_xor(mx, 4));
            mx = fmaxf(mx, __shfl_xor(mx, 8));
            float e = expf(x - mx);
            float s = e;
            s += __shfl_xor(s, 1);
            s += __shfl_xor(s, 2);
            s += __shfl_xor(s, 4);
            s += __shfl_xor(s, 8);
            pwv[m][r] = e / s;
        }
    }

    // ---- epilogue: bias + exact GELU -> swizzled bf16 zs (wave-private) ---
    {
        char* zb = (char*)zs;
        #pragma unroll
        for (int n = 0; n < 16; ++n) {
            float tb = trunk_b[n * 16 + lr];
            #pragma unroll
            for (int m = 0; m < 2; ++m)
            #pragma unroll
            for (int r = 0; r < 4; ++r) {
                float v = acc[m][n][r] + tb;
                v = 0.5f * v * (1.f + erff(v * 0.70710678118654752f));
                int row  = w * 32 + m * 16 + lg * 4 + r;
                int col  = n * 16 + lr;
                int slot = (col >> 3) ^ (row & 7);
                *(ushort*)(zb + row * 512 + slot * 16 + (col & 7) * 2) = f2bf(v);
            }
        }
    }
    // no __syncthreads: each wave reads only rows it wrote; compiler orders
    // same-wave LDS write->read with lgkmcnt.

    // ---- phase C: head GEMM [32 x 320] per wave, K=256 --------------------
    const char* zb = (const char*)zs;
    const int p8 = l & 7;
    const int csrc = (l & 48) | (p8 ? (p8 - 1) : 0);
    const int row0 = w * 32 + lr;
    const int row1 = row0 + 16;

    f32x4 acc2[2][20];
    #pragma unroll
    for (int m = 0; m < 2; ++m)
    #pragma unroll
    for (int n = 0; n < 20; ++n) acc2[m][n] = (f32x4){0.f, 0.f, 0.f, 0.f};

    #pragma unroll
    for (int kk = 0; kk < 8; ++kk) {
        short8 a0 = *(const short8*)(zb + row0 * 512 + (((kk * 4 + lg) ^ (row0 & 7)) << 4));
        short8 a1 = *(const short8*)(zb + row1 * 512 + (((kk * 4 + lg) ^ (row1 & 7)) << 4));
        const ushort* wp = WaP + (size_t)(kk * 20) * 64 * 8;
        #pragma unroll
        for (int n = 0; n < 20; ++n) {
            short8 bq = *(const short8*)(wp + ((size_t)n * 64 + l) * 8);
            acc2[0][n] = __builtin_amdgcn_mfma_f32_16x16x32_bf16(a0, bq, acc2[0][n], 0, 0, 0);
            acc2[1][n] = __builtin_amdgcn_mfma_f32_16x16x32_bf16(a1, bq, acc2[1][n], 0, 0, 0);
        }
    }

    // ---- phase E: bias, phase-weighted 8-lane reduce, store ---------------
    {
        float cw[2][4];
        #pragma unroll
        for (int m = 0; m < 2; ++m)
        #pragma unroll
        for (int r = 0; r < 4; ++r)
            cw[m][r] = __shfl(pwv[m][r], csrc);

        #pragma unroll
        for (int n = 0; n < 20; ++n) {
            float wb = wbias[n * 16 + lr];
            #pragma unroll
            for (int m = 0; m < 2; ++m)
            #pragma unroll
            for (int r = 0; r < 4; ++r) {
                float e = acc2[m][n][r] + wb;
                float val = (p8 ? cw[m][r] : 1.0f) * e;
                val += __shfl_xor(val, 1);
                val += __shfl_xor(val, 2);
                val += __shfl_xor(val, 4);
                if (p8 == 0) {
                    int combo = n * 16 + lr;
                    int h = combo / 160, rem = combo % 160, kb = rem >> 3;
                    size_t t = block0 + w * 32 + m * 16 + lg * 4 + r;
                    out[(size_t)h * (BT * BINS) + t * BINS + kb] = val;
                }
            }
        }
    }
}

// ---------------------------------------------------------------------------
extern "C" void kernel_launch(void* const* d_in, const int* in_sizes, int n_in,
                              void* d_out, int out_size, void* d_ws, size_t ws_size,
                              hipStream_t stream) {
    const float* h_t          = (const float*)d_in[0];
    const float* a_t          = (const float*)d_in[1];
    const float* d_t          = (const float*)d_in[2];
    const float* age_embed    = (const float*)d_in[3];
    const float* trunk_w      = (const float*)d_in[4];
    const float* trunk_b      = (const float*)d_in[5];
    const float* inst_base_w  = (const float*)d_in[6];
    const float* inst_base_b  = (const float*)d_in[7];
    const float* group_base_w = (const float*)d_in[8];
    const float* group_base_b = (const float*)d_in[9];
    const float* inst_exp_w   = (const float*)d_in[10];
    const float* inst_exp_b   = (const float*)d_in[11];
    const float* group_exp_w  = (const float*)d_in[12];
    const float* group_exp_b  = (const float*)d_in[13];
    const float* router_w     = (const float*)d_in[14];
    const float* router_b     = (const float*)d_in[15];

    ushort* WtP   = (ushort*)d_ws;
    ushort* RP    = WtP + WT_P_SZ;
    ushort* WaP   = RP + RP_SZ;
    float*  wbias = (float*)(WaP + WA_P_SZ);

    pack_all<<<481, 64, 0, stream>>>(
        trunk_w, router_w,
        inst_base_w, inst_base_b, group_base_w, group_base_b,
        inst_exp_w, inst_exp_b, group_exp_w, group_exp_b,
        WtP, RP, WaP, wbias);

    fused_mfma<<<BT / 128, 256, 0, stream>>>(
        h_t, a_t, d_t, age_embed, trunk_b, router_b,
        WtP, RP, WaP, wbias, (float*)d_out);
}

// Round 4
// 167.160 us; speedup vs baseline: 1.0960x; 1.0960x over previous
//
#include <hip/hip_runtime.h>
#include <math.h>

typedef unsigned int uint;
typedef unsigned short ushort;

using short8 = __attribute__((ext_vector_type(8))) short;
using f32x4  = __attribute__((ext_vector_type(4))) float;

#define BT      65536
#define HID     512
#define IN_DIM  594
#define TRUNK   256
#define BINS    20
#define NCOMBO  320

#define WT_P_SZ (19*16*64*8)
#define RP_SZ   (16*64*8)
#define WA_P_SZ (8*20*64*8)

__device__ inline ushort f2bf(float f) {
    uint u = __float_as_uint(f);
    return (ushort)((u + 0x7fffu + ((u >> 16) & 1u)) >> 16);   // RNE
}

// ---------------------------------------------------------------------------
// Pack weights to bf16 MFMA B-fragment layout (verified R2/R3):
//   frag elem j, lane l, frag (kk,n): B[k][col], k=kk*32+(l>>4)*8+j, col=n*16+(l&15)
// ---------------------------------------------------------------------------
__global__ __launch_bounds__(64) void pack_all(
    const float* __restrict__ trunk_w, const float* __restrict__ router_w,
    const float* __restrict__ inst_base_w, const float* __restrict__ inst_base_b,
    const float* __restrict__ group_base_w, const float* __restrict__ group_base_b,
    const float* __restrict__ inst_exp_w, const float* __restrict__ inst_exp_b,
    const float* __restrict__ group_exp_w, const float* __restrict__ group_exp_b,
    ushort* __restrict__ WtP, ushort* __restrict__ RP,
    ushort* __restrict__ WaP, float* __restrict__ wbias)
{
    const int b = blockIdx.x, l = threadIdx.x;
    const int lr = l & 15, lg = l >> 4;
    if (b < 304) {                      // trunk: kk 0..18, n 0..15
        int kk = b >> 4, n = b & 15;
        int col = n * 16 + lr;
        ushort* dst = WtP + ((size_t)(kk * 16 + n) * 64 + l) * 8;
        #pragma unroll
        for (int j = 0; j < 8; ++j) {
            int k = kk * 32 + lg * 8 + j;
            dst[j] = (k < IN_DIM) ? f2bf(trunk_w[k * TRUNK + col]) : (ushort)0;
        }
    } else if (b < 320) {               // router: kk 0..15
        int kk = b - 304;
        ushort* dst = RP + ((size_t)(kk * 64 + l)) * 8;
        #pragma unroll
        for (int j = 0; j < 8; ++j) {
            int k = kk * 32 + lg * 8 + j;
            dst[j] = (lr < 7) ? f2bf(router_w[k * 7 + lr]) : (ushort)0;
        }
    } else if (b < 480) {               // heads: kk 0..7, n 0..19
        int b2 = b - 320, kk = b2 / 20, n = b2 % 20;
        int combo = n * 16 + lr;
        int h = combo / 160, rem = combo % 160, kb = rem >> 3, p = rem & 7;
        const float* bw = h ? group_base_w : inst_base_w;
        const float* ew = h ? group_exp_w  : inst_exp_w;
        ushort* dst = WaP + ((size_t)(kk * 20 + n) * 64 + l) * 8;
        #pragma unroll
        for (int j = 0; j < 8; ++j) {
            int k = kk * 32 + lg * 8 + j;
            float v = (p == 0) ? bw[k * BINS + kb]
                               : ew[((p - 1) * TRUNK + k) * BINS + kb];
            dst[j] = f2bf(v);
        }
    } else {                            // bias[320]
        for (int c = l; c < NCOMBO; c += 64) {
            int h = c / 160, rem = c % 160, kb = rem >> 3, p = rem & 7;
            const float* bb = h ? group_base_b : inst_base_b;
            const float* eb = h ? group_exp_b  : inst_exp_b;
            wbias[c] = (p == 0) ? bb[kb] : eb[(p - 1) * BINS + kb];
        }
    }
}

// ---------------------------------------------------------------------------
// Fused main: 64 tokens/block, 4 waves, wave w owns rows w*16..+15.
// 16 rows/wave doubles wave count -> 4 waves/SIMD for latency hiding.
// Direct-global A-frags, zero barriers, wave-private swizzled zs (32 KB).
// ---------------------------------------------------------------------------
__global__ __launch_bounds__(256, 4) void fused_mfma(
    const float* __restrict__ h_t, const float* __restrict__ a_t,
    const float* __restrict__ d_t, const float* __restrict__ age,
    const float* __restrict__ trunk_b, const float* __restrict__ router_b,
    const ushort* __restrict__ WtP, const ushort* __restrict__ RP,
    const ushort* __restrict__ WaP, const float* __restrict__ wbias,
    float* __restrict__ out)
{
    __shared__ alignas(16) ushort zs[64 * 256];   // 32 KB

    const int tid = threadIdx.x;
    const int l = tid & 63, w = tid >> 6;
    const int lr = l & 15, lg = l >> 4;
    const int block0 = blockIdx.x * 64;
    const size_t tok = block0 + w * 16 + lr;      // this lane's A-frag row

    f32x4 acc[16];
    f32x4 accr = (f32x4){0.f, 0.f, 0.f, 0.f};
    #pragma unroll
    for (int n = 0; n < 16; ++n) acc[n] = (f32x4){0.f, 0.f, 0.f, 0.f};

    auto cvt8 = [](float4 a, float4 b) -> short8 {
        short8 v;
        v[0] = (short)f2bf(a.x); v[1] = (short)f2bf(a.y);
        v[2] = (short)f2bf(a.z); v[3] = (short)f2bf(a.w);
        v[4] = (short)f2bf(b.x); v[5] = (short)f2bf(b.y);
        v[6] = (short)f2bf(b.z); v[7] = (short)f2bf(b.w);
        return v;
    };

    // ---- phase A: trunk (K=608) + router (K=512), direct-global A ---------
    #pragma unroll 4
    for (int kk = 0; kk < 16; ++kk) {               // h_t chunks
        const float4* p0 = (const float4*)(h_t + tok * HID + kk * 32 + lg * 8);
        float4 f0 = p0[0], f1 = p0[1];
        short8 a0 = cvt8(f0, f1);

        short8 rb = *(const short8*)(RP + ((size_t)(kk * 64 + l)) * 8);
        accr = __builtin_amdgcn_mfma_f32_16x16x32_bf16(a0, rb, accr, 0, 0, 0);

        const ushort* wp = WtP + (size_t)kk * 16 * 64 * 8;
        #pragma unroll
        for (int n = 0; n < 16; ++n) {
            short8 bq = *(const short8*)(wp + ((size_t)n * 64 + l) * 8);
            acc[n] = __builtin_amdgcn_mfma_f32_16x16x32_bf16(a0, bq, acc[n], 0, 0, 0);
        }
    }
    #pragma unroll
    for (int kk = 16; kk < 18; ++kk) {              // a_t chunks
        const float4* p0 = (const float4*)(a_t + tok * 64 + (kk - 16) * 32 + lg * 8);
        float4 f0 = p0[0], f1 = p0[1];
        short8 a0 = cvt8(f0, f1);
        const ushort* wp = WtP + (size_t)kk * 16 * 64 * 8;
        #pragma unroll
        for (int n = 0; n < 16; ++n) {
            short8 bq = *(const short8*)(wp + ((size_t)n * 64 + l) * 8);
            acc[n] = __builtin_amdgcn_mfma_f32_16x16x32_bf16(a0, bq, acc[n], 0, 0, 0);
        }
    }
    {                                               // tail chunk kk=18
        short8 a0;
        #pragma unroll
        for (int j = 0; j < 8; ++j) {
            int c = 576 + lg * 8 + j;
            float v;
            if (c < 578)      v = d_t[tok * 2 + (c - 576)];
            else if (c < 594) v = age[tok * 16 + (c - 578)];
            else              v = 0.f;
            a0[j] = (short)f2bf(v);
        }
        const ushort* wp = WtP + (size_t)18 * 16 * 64 * 8;
        #pragma unroll
        for (int n = 0; n < 16; ++n) {
            short8 bq = *(const short8*)(wp + ((size_t)n * 64 + l) * 8);
            acc[n] = __builtin_amdgcn_mfma_f32_16x16x32_bf16(a0, bq, acc[n], 0, 0, 0);
        }
    }

    // ---- router softmax in registers --------------------------------------
    // lane l holds logit for row = w*16 + lg*4 + r, phase p = lr (p<7)
    float pwv[4];
    {
        const float rb_l = (lr < 7) ? router_b[lr] : 0.f;
        #pragma unroll
        for (int r = 0; r < 4; ++r) {
            float x = (lr < 7) ? (accr[r] + rb_l) : -3.0e38f;
            float mx = x;
            mx = fmaxf(mx, __shfl_xor(mx, 1));
            mx = fmaxf(mx, __shfl_xor(mx, 2));
            mx = fmaxf(mx, __shfl_xor(mx, 4));
            mx = fmaxf(mx, __shfl_xor(mx, 8));
            float e = expf(x - mx);
            float s = e;
            s += __shfl_xor(s, 1);
            s += __shfl_xor(s, 2);
            s += __shfl_xor(s, 4);
            s += __shfl_xor(s, 8);
            pwv[r] = e / s;
        }
    }

    // ---- epilogue: bias + exact GELU -> swizzled bf16 zs (wave-private) ---
    {
        char* zb = (char*)zs;
        #pragma unroll
        for (int n = 0; n < 16; ++n) {
            float tb = trunk_b[n * 16 + lr];
            #pragma unroll
            for (int r = 0; r < 4; ++r) {
                float v = acc[n][r] + tb;
                v = 0.5f * v * (1.f + erff(v * 0.70710678118654752f));
                int row  = w * 16 + lg * 4 + r;
                int col  = n * 16 + lr;
                int slot = (col >> 3) ^ (row & 7);
                *(ushort*)(zb + row * 512 + slot * 16 + (col & 7) * 2) = f2bf(v);
            }
        }
    }
    // no __syncthreads: each wave reads only rows it wrote (same-wave lgkmcnt)

    // ---- phase C: head GEMM [16 x 320] per wave, K=256 --------------------
    const char* zb = (const char*)zs;
    const int p8 = l & 7;
    const int csrc = (l & 48) | (p8 ? (p8 - 1) : 0);
    const int row0 = w * 16 + lr;

    f32x4 acc2[20];
    #pragma unroll
    for (int n = 0; n < 20; ++n) acc2[n] = (f32x4){0.f, 0.f, 0.f, 0.f};

    #pragma unroll
    for (int kk = 0; kk < 8; ++kk) {
        short8 a0 = *(const short8*)(zb + row0 * 512 + (((kk * 4 + lg) ^ (row0 & 7)) << 4));
        const ushort* wp = WaP + (size_t)(kk * 20) * 64 * 8;
        #pragma unroll
        for (int n = 0; n < 20; ++n) {
            short8 bq = *(const short8*)(wp + ((size_t)n * 64 + l) * 8);
            acc2[n] = __builtin_amdgcn_mfma_f32_16x16x32_bf16(a0, bq, acc2[n], 0, 0, 0);
        }
    }

    // ---- phase E: bias, phase-weighted 8-lane reduce, store ---------------
    {
        float cw[4];
        #pragma unroll
        for (int r = 0; r < 4; ++r)
            cw[r] = __shfl(pwv[r], csrc);

        #pragma unroll
        for (int n = 0; n < 20; ++n) {
            float wb = wbias[n * 16 + lr];
            #pragma unroll
            for (int r = 0; r < 4; ++r) {
                float e = acc2[n][r] + wb;
                float val = (p8 ? cw[r] : 1.0f) * e;
                val += __shfl_xor(val, 1);
                val += __shfl_xor(val, 2);
                val += __shfl_xor(val, 4);
                if (p8 == 0) {
                    int combo = n * 16 + lr;
                    int h = combo / 160, rem = combo % 160, kb = rem >> 3;
                    size_t t = block0 + w * 16 + lg * 4 + r;
                    out[(size_t)h * (BT * BINS) + t * BINS + kb] = val;
                }
            }
        }
    }
}

// ---------------------------------------------------------------------------
extern "C" void kernel_launch(void* const* d_in, const int* in_sizes, int n_in,
                              void* d_out, int out_size, void* d_ws, size_t ws_size,
                              hipStream_t stream) {
    const float* h_t          = (const float*)d_in[0];
    const float* a_t          = (const float*)d_in[1];
    const float* d_t          = (const float*)d_in[2];
    const float* age_embed    = (const float*)d_in[3];
    const float* trunk_w      = (const float*)d_in[4];
    const float* trunk_b      = (const float*)d_in[5];
    const float* inst_base_w  = (const float*)d_in[6];
    const float* inst_base_b  = (const float*)d_in[7];
    const float* group_base_w = (const float*)d_in[8];
    const float* group_base_b = (const float*)d_in[9];
    const float* inst_exp_w   = (const float*)d_in[10];
    const float* inst_exp_b   = (const float*)d_in[11];
    const float* group_exp_w  = (const float*)d_in[12];
    const float* group_exp_b  = (const float*)d_in[13];
    const float* router_w     = (const float*)d_in[14];
    const float* router_b     = (const float*)d_in[15];

    ushort* WtP   = (ushort*)d_ws;
    ushort* RP    = WtP + WT_P_SZ;
    ushort* WaP   = RP + RP_SZ;
    float*  wbias = (float*)(WaP + WA_P_SZ);

    pack_all<<<481, 64, 0, stream>>>(
        trunk_w, router_w,
        inst_base_w, inst_base_b, group_base_w, group_base_b,
        inst_exp_w, inst_exp_b, group_exp_w, group_exp_b,
        WtP, RP, WaP, wbias);

    fused_mfma<<<BT / 64, 256, 0, stream>>>(
        h_t, a_t, d_t, age_embed, trunk_b, router_b,
        WtP, RP, WaP, wbias, (float*)d_out);
}

// Round 5
// 92.762 us; speedup vs baseline: 1.9750x; 1.8020x over previous
//
#include <hip/hip_runtime.h>
#include <math.h>

typedef unsigned int uint;
typedef unsigned short ushort;

using short8 = __attribute__((ext_vector_type(8))) short;
using f32x4  = __attribute__((ext_vector_type(4))) float;

#define BT      65536
#define HID     512
#define IN_DIM  594
#define TRUNK   256
#define BINS    20
#define NCOMBO  320

#define WT_P_SZ (19*16*64*8)
#define RP_SZ   (16*64*8)
#define WA_P_SZ (8*20*64*8)

__device__ inline ushort f2bf(float f) {
    uint u = __float_as_uint(f);
    return (ushort)((u + 0x7fffu + ((u >> 16) & 1u)) >> 16);   // RNE
}

// ---------------------------------------------------------------------------
// Pack weights to bf16 MFMA B-fragment layout (verified R2-R4):
//   frag elem j, lane l, frag (kk,n): B[k][col], k=kk*32+(l>>4)*8+j, col=n*16+(l&15)
// ---------------------------------------------------------------------------
__global__ __launch_bounds__(64) void pack_all(
    const float* __restrict__ trunk_w, const float* __restrict__ router_w,
    const float* __restrict__ inst_base_w, const float* __restrict__ inst_base_b,
    const float* __restrict__ group_base_w, const float* __restrict__ group_base_b,
    const float* __restrict__ inst_exp_w, const float* __restrict__ inst_exp_b,
    const float* __restrict__ group_exp_w, const float* __restrict__ group_exp_b,
    ushort* __restrict__ WtP, ushort* __restrict__ RP,
    ushort* __restrict__ WaP, float* __restrict__ wbias)
{
    const int b = blockIdx.x, l = threadIdx.x;
    const int lr = l & 15, lg = l >> 4;
    if (b < 304) {                      // trunk: kk 0..18, n 0..15
        int kk = b >> 4, n = b & 15;
        int col = n * 16 + lr;
        ushort* dst = WtP + ((size_t)(kk * 16 + n) * 64 + l) * 8;
        #pragma unroll
        for (int j = 0; j < 8; ++j) {
            int k = kk * 32 + lg * 8 + j;
            dst[j] = (k < IN_DIM) ? f2bf(trunk_w[k * TRUNK + col]) : (ushort)0;
        }
    } else if (b < 320) {               // router: kk 0..15
        int kk = b - 304;
        ushort* dst = RP + ((size_t)(kk * 64 + l)) * 8;
        #pragma unroll
        for (int j = 0; j < 8; ++j) {
            int k = kk * 32 + lg * 8 + j;
            dst[j] = (lr < 7) ? f2bf(router_w[k * 7 + lr]) : (ushort)0;
        }
    } else if (b < 480) {               // heads: kk 0..7, n 0..19
        int b2 = b - 320, kk = b2 / 20, n = b2 % 20;
        int combo = n * 16 + lr;
        int h = combo / 160, rem = combo % 160, kb = rem >> 3, p = rem & 7;
        const float* bw = h ? group_base_w : inst_base_w;
        const float* ew = h ? group_exp_w  : inst_exp_w;
        ushort* dst = WaP + ((size_t)(kk * 20 + n) * 64 + l) * 8;
        #pragma unroll
        for (int j = 0; j < 8; ++j) {
            int k = kk * 32 + lg * 8 + j;
            float v = (p == 0) ? bw[k * BINS + kb]
                               : ew[((p - 1) * TRUNK + k) * BINS + kb];
            dst[j] = f2bf(v);
        }
    } else {                            // bias[320]
        for (int c = l; c < NCOMBO; c += 64) {
            int h = c / 160, rem = c % 160, kb = rem >> 3, p = rem & 7;
            const float* bb = h ? group_base_b : inst_base_b;
            const float* eb = h ? group_exp_b  : inst_exp_b;
            wbias[c] = (p == 0) ? bb[kb] : eb[(p - 1) * BINS + kb];
        }
    }
}

// ---------------------------------------------------------------------------
// Fused main: 128 tokens/block, 4 waves, N-SPLIT trunk:
//   wave w computes trunk N-frags w*4..w*4+3 (cols w*64..+63) for ALL 128 rows.
//   Each trunk weight frag read by exactly one wave -> 4x less L2 weight traffic.
// x staged in LDS in A-FRAGMENT layout (lane-linear, conflict-free), dbuf.
// Head phase M-split (wave w: rows w*32..+31), hf-split to cap registers.
// LDS: zs[128][256] bf16 swizzled (64 KB), unioned with xs[2][8KB].
// ---------------------------------------------------------------------------
__global__ __launch_bounds__(256, 2) void fused_mfma(
    const float* __restrict__ h_t, const float* __restrict__ a_t,
    const float* __restrict__ d_t, const float* __restrict__ age,
    const float* __restrict__ trunk_b, const float* __restrict__ router_b,
    const ushort* __restrict__ WtP, const ushort* __restrict__ RP,
    const ushort* __restrict__ WaP, const float* __restrict__ wbias,
    float* __restrict__ out)
{
    __shared__ alignas(16) ushort zs[32768];   // 64 KB; first 8192 ushorts = xs[2]

    const int tid = threadIdx.x;
    const int l = tid & 63, w = tid >> 6;
    const int lr = l & 15, lg = l >> 4;
    const int block0 = blockIdx.x * 128;

    // staging mapping: thread -> (row, 16-col half of 32-col chunk)
    const int srow = tid >> 1;
    const int half = tid & 1;
    const size_t stok = block0 + srow;

    ushort* xs = zs;                 // xs[buf][frag mm][lane*8], buf stride 4096

    f32x4 acc[8][4];                 // [M-frag][N-frag] 128 VGPRs
    f32x4 accr0 = (f32x4){0.f,0.f,0.f,0.f};   // router, M-frag 2w
    f32x4 accr1 = (f32x4){0.f,0.f,0.f,0.f};   // router, M-frag 2w+1
    #pragma unroll
    for (int mm = 0; mm < 8; ++mm)
    #pragma unroll
    for (int nn = 0; nn < 4; ++nn) acc[mm][nn] = (f32x4){0.f,0.f,0.f,0.f};

    auto stage_load = [&](int kk, float4 ld[4]) {
        if (kk < 16) {
            const float4* p = (const float4*)(h_t + stok * HID + kk * 32 + half * 16);
            ld[0]=p[0]; ld[1]=p[1]; ld[2]=p[2]; ld[3]=p[3];
        } else if (kk < 18) {
            const float4* p = (const float4*)(a_t + stok * 64 + (kk - 16) * 32 + half * 16);
            ld[0]=p[0]; ld[1]=p[1]; ld[2]=p[2]; ld[3]=p[3];
        } else {
            float* f = (float*)ld;
            #pragma unroll
            for (int j = 0; j < 16; ++j) {
                int c = 576 + half * 16 + j;
                float v;
                if (c < 578)      v = d_t[stok * 2 + (c - 576)];
                else if (c < 594) v = age[stok * 16 + (c - 578)];
                else              v = 0.f;
                f[j] = v;
            }
        }
    };
    // write 16 values into A-frag layout: frag mm=srow>>4,
    // lanes (srow&15)+half*32 and +16, 16 B each (2-way LDS, free)
    auto stage_write = [&](int buf, float4 ld[4]) {
        const float* f = (const float*)ld;
        short8 v0, v1;
        #pragma unroll
        for (int j = 0; j < 8; ++j) {
            v0[j] = (short)f2bf(f[j]);
            v1[j] = (short)f2bf(f[j + 8]);
        }
        ushort* dst = xs + buf * 4096 + (srow >> 4) * 512 + ((srow & 15) + half * 32) * 8;
        *(short8*)dst = v0;
        *(short8*)(dst + 128) = v1;    // lane + 16
    };

    // ---- phase A: trunk (K=608, N-split) + router (K=512, per-wave rows) --
    {
        float4 ld[4];
        stage_load(0, ld);
        stage_write(0, ld);
        __syncthreads();
        int cur = 0;
        const int w4 = w * 4;
        #pragma unroll 1
        for (int kk = 0; kk < 19; ++kk) {
            float4 nld[4];
            if (kk < 18) stage_load(kk + 1, nld);

            // B-frags for this wave's N-slice (L2, wave-exclusive)
            const ushort* wp = WtP + ((size_t)kk * 16 + w4) * 512;
            short8 bq0 = *(const short8*)(wp + 0 * 512 + l * 8);
            short8 bq1 = *(const short8*)(wp + 1 * 512 + l * 8);
            short8 bq2 = *(const short8*)(wp + 2 * 512 + l * 8);
            short8 bq3 = *(const short8*)(wp + 3 * 512 + l * 8);

            // A-frags from LDS (lane-linear, conflict-free)
            const ushort* xb = xs + cur * 4096;
            short8 a0 = *(const short8*)(xb + 0 * 512 + l * 8);
            short8 a1 = *(const short8*)(xb + 1 * 512 + l * 8);
            short8 a2 = *(const short8*)(xb + 2 * 512 + l * 8);
            short8 a3 = *(const short8*)(xb + 3 * 512 + l * 8);
            short8 a4 = *(const short8*)(xb + 4 * 512 + l * 8);
            short8 a5 = *(const short8*)(xb + 5 * 512 + l * 8);
            short8 a6 = *(const short8*)(xb + 6 * 512 + l * 8);
            short8 a7 = *(const short8*)(xb + 7 * 512 + l * 8);

            if (kk < 16) {   // router for this wave's head rows (M-frags 2w,2w+1)
                short8 rb = *(const short8*)(RP + (size_t)kk * 512 + l * 8);
                short8 ar0 = *(const short8*)(xb + (w * 2 + 0) * 512 + l * 8);
                short8 ar1 = *(const short8*)(xb + (w * 2 + 1) * 512 + l * 8);
                accr0 = __builtin_amdgcn_mfma_f32_16x16x32_bf16(ar0, rb, accr0, 0, 0, 0);
                accr1 = __builtin_amdgcn_mfma_f32_16x16x32_bf16(ar1, rb, accr1, 0, 0, 0);
            }

            #define TRUNK_MM(AF) \
                acc[0][0] = __builtin_amdgcn_mfma_f32_16x16x32_bf16(AF, bq0, acc[0][0],0,0,0);
            // (expanded manually below for all mm,nn)
            #undef TRUNK_MM
            #pragma unroll
            for (int nn = 0; nn < 4; ++nn) {
                short8 bq = (nn == 0) ? bq0 : (nn == 1) ? bq1 : (nn == 2) ? bq2 : bq3;
                acc[0][nn] = __builtin_amdgcn_mfma_f32_16x16x32_bf16(a0, bq, acc[0][nn],0,0,0);
                acc[1][nn] = __builtin_amdgcn_mfma_f32_16x16x32_bf16(a1, bq, acc[1][nn],0,0,0);
                acc[2][nn] = __builtin_amdgcn_mfma_f32_16x16x32_bf16(a2, bq, acc[2][nn],0,0,0);
                acc[3][nn] = __builtin_amdgcn_mfma_f32_16x16x32_bf16(a3, bq, acc[3][nn],0,0,0);
                acc[4][nn] = __builtin_amdgcn_mfma_f32_16x16x32_bf16(a4, bq, acc[4][nn],0,0,0);
                acc[5][nn] = __builtin_amdgcn_mfma_f32_16x16x32_bf16(a5, bq, acc[5][nn],0,0,0);
                acc[6][nn] = __builtin_amdgcn_mfma_f32_16x16x32_bf16(a6, bq, acc[6][nn],0,0,0);
                acc[7][nn] = __builtin_amdgcn_mfma_f32_16x16x32_bf16(a7, bq, acc[7][nn],0,0,0);
            }

            if (kk < 18) stage_write(cur ^ 1, nld);
            __syncthreads();
            cur ^= 1;
        }
    }

    // ---- router softmax in registers (rows w*32..+31) ---------------------
    float pwv[2][4];
    {
        const float rb_l = (lr < 7) ? router_b[lr] : 0.f;
        #pragma unroll
        for (int m = 0; m < 2; ++m)
        #pragma unroll
        for (int r = 0; r < 4; ++r) {
            float lv = (m == 0) ? accr0[r] : accr1[r];
            float x = (lr < 7) ? (lv + rb_l) : -3.0e38f;
            float mx = x;
            mx = fmaxf(mx, __shfl_xor(mx, 1));
            mx = fmaxf(mx, __shfl_xor(mx, 2));
            mx = fmaxf(mx, __shfl_xor(mx, 4));
            mx = fmaxf(mx, __shfl_xor(mx, 8));
            float e = expf(x - mx);
            float s = e;
            s += __shfl_xor(s, 1);
            s += __shfl_xor(s, 2);
            s += __shfl_xor(s, 4);
            s += __shfl_xor(s, 8);
            pwv[m][r] = e / s;
        }
    }

    // ---- epilogue: bias + exact GELU -> swizzled bf16 zs ------------------
    // wave w writes cols w*64..+63 for all 128 rows (xs region dead now)
    {
        char* zb = (char*)zs;
        #pragma unroll
        for (int nn = 0; nn < 4; ++nn) {
            float tb = trunk_b[(w * 4 + nn) * 16 + lr];
            int colbase = (w * 4 + nn) * 16 + lr;
            #pragma unroll
            for (int mm = 0; mm < 8; ++mm)
            #pragma unroll
            for (int r = 0; r < 4; ++r) {
                float v = acc[mm][nn][r] + tb;
                v = 0.5f * v * (1.f + erff(v * 0.70710678118654752f));
                int row  = mm * 16 + lg * 4 + r;
                int slot = (colbase >> 3) ^ (row & 7);
                *(ushort*)(zb + row * 512 + slot * 16 + (colbase & 7) * 2) = f2bf(v);
            }
        }
    }
    __syncthreads();   // zs written N-split, read M-split (cross-wave)

    // ---- phase C: head GEMM, M-split: wave w rows w*32..+31, K=256 --------
    const char* zb = (const char*)zs;
    const int p8 = l & 7;
    const int csrc = (l & 48) | (p8 ? (p8 - 1) : 0);
    const int row0 = w * 32 + lr;
    const int row1 = row0 + 16;      // (row1&7)==(row0&7)

    float cw[2][4];
    #pragma unroll
    for (int m = 0; m < 2; ++m)
    #pragma unroll
    for (int r = 0; r < 4; ++r)
        cw[m][r] = __shfl(pwv[m][r], csrc);

    #pragma unroll 1
    for (int hf = 0; hf < 2; ++hf) {
        f32x4 acc2[2][10];
        #pragma unroll
        for (int m = 0; m < 2; ++m)
        #pragma unroll
        for (int n = 0; n < 10; ++n) acc2[m][n] = (f32x4){0.f,0.f,0.f,0.f};
        float wb_[10];
        #pragma unroll
        for (int n = 0; n < 10; ++n) wb_[n] = wbias[(hf * 10 + n) * 16 + lr];

        #pragma unroll
        for (int kk = 0; kk < 8; ++kk) {
            short8 a0 = *(const short8*)(zb + row0 * 512 + (((kk * 4 + lg) ^ (row0 & 7)) << 4));
            short8 a1 = *(const short8*)(zb + row1 * 512 + (((kk * 4 + lg) ^ (row1 & 7)) << 4));
            const ushort* wp = WaP + (size_t)(kk * 20 + hf * 10) * 512;
            #pragma unroll
            for (int n = 0; n < 10; ++n) {
                short8 bq = *(const short8*)(wp + (size_t)n * 512 + l * 8);
                acc2[0][n] = __builtin_amdgcn_mfma_f32_16x16x32_bf16(a0, bq, acc2[0][n],0,0,0);
                acc2[1][n] = __builtin_amdgcn_mfma_f32_16x16x32_bf16(a1, bq, acc2[1][n],0,0,0);
            }
        }

        // ---- phase E: bias, phase-weighted 8-lane reduce, store -----------
        #pragma unroll
        for (int m = 0; m < 2; ++m)
        #pragma unroll
        for (int n = 0; n < 10; ++n)
        #pragma unroll
        for (int r = 0; r < 4; ++r) {
            float e = acc2[m][n][r] + wb_[n];
            float val = (p8 ? cw[m][r] : 1.0f) * e;
            val += __shfl_xor(val, 1);
            val += __shfl_xor(val, 2);
            val += __shfl_xor(val, 4);
            if (p8 == 0) {
                int combo = (hf * 10 + n) * 16 + lr;
                int h = combo / 160, rem = combo % 160, kb = rem >> 3;
                size_t t = block0 + w * 32 + m * 16 + lg * 4 + r;
                out[(size_t)h * (BT * BINS) + t * BINS + kb] = val;
            }
        }
    }
}

// ---------------------------------------------------------------------------
extern "C" void kernel_launch(void* const* d_in, const int* in_sizes, int n_in,
                              void* d_out, int out_size, void* d_ws, size_t ws_size,
                              hipStream_t stream) {
    const float* h_t          = (const float*)d_in[0];
    const float* a_t          = (const float*)d_in[1];
    const float* d_t          = (const float*)d_in[2];
    const float* age_embed    = (const float*)d_in[3];
    const float* trunk_w      = (const float*)d_in[4];
    const float* trunk_b      = (const float*)d_in[5];
    const float* inst_base_w  = (const float*)d_in[6];
    const float* inst_base_b  = (const float*)d_in[7];
    const float* group_base_w = (const float*)d_in[8];
    const float* group_base_b = (const float*)d_in[9];
    const float* inst_exp_w   = (const float*)d_in[10];
    const float* inst_exp_b   = (const float*)d_in[11];
    const float* group_exp_w  = (const float*)d_in[12];
    const float* group_exp_b  = (const float*)d_in[13];
    const float* router_w     = (const float*)d_in[14];
    const float* router_b     = (const float*)d_in[15];

    ushort* WtP   = (ushort*)d_ws;
    ushort* RP    = WtP + WT_P_SZ;
    ushort* WaP   = RP + RP_SZ;
    float*  wbias = (float*)(WaP + WA_P_SZ);

    pack_all<<<481, 64, 0, stream>>>(
        trunk_w, router_w,
        inst_base_w, inst_base_b, group_base_w, group_base_b,
        inst_exp_w, inst_exp_b, group_exp_w, group_exp_b,
        WtP, RP, WaP, wbias);

    fused_mfma<<<BT / 128, 256, 0, stream>>>(
        h_t, a_t, d_t, age_embed, trunk_b, router_b,
        WtP, RP, WaP, wbias, (float*)d_out);
}